// Round 12
// baseline (257.523 us; speedup 1.0000x reference)
//
#include <hip/hip_runtime.h>
#include <hip/hip_bf16.h>

#define D_DIM 512
#define K_CL  2048

#define AS1 __attribute__((address_space(1)))
#define AS3 __attribute__((address_space(3)))

typedef short s8v __attribute__((ext_vector_type(8)));
typedef float f4v __attribute__((ext_vector_type(4)));

__device__ __forceinline__ void gload16(const void* g, void* l) {
    // async global->LDS, 16B/lane; LDS dest = wave-uniform base + lane*16
    __builtin_amdgcn_global_load_lds((const AS1 void*)g, (AS3 void*)l, 16, 0, 0);
}

// ---- merged prep: fp32 -> bf16 packed-tile images + row sum-of-squares -----
// Rows [0,n) = features -> Fp/f2; rows [n,n+k) = prototypes -> Pp/p2.
// Packed image: per 128-row panel pb, per 32-k chunk c: 4096-ushort block at
// (pb*16+c)*4096; row r at r*32, k-octet j at slot (j ^ ((r>>1)&3))*8.
__global__ void prep_kernel(const float* __restrict__ F,
                            const float* __restrict__ P,
                            ushort* __restrict__ Fp,
                            ushort* __restrict__ Pp,
                            float* __restrict__ f2,
                            float* __restrict__ p2,
                            int n, int ntot) {
    int grow = (int)((blockIdx.x * blockDim.x + threadIdx.x) >> 6);
    int lane = threadIdx.x & 63;
    if (grow >= ntot) return;

    const bool isP = grow >= n;
    const int  row = isP ? grow - n : grow;
    const float* s = (isP ? P : F) + (size_t)row * D_DIM + lane * 8;

    float4 v0 = *reinterpret_cast<const float4*>(s);
    float4 v1 = *reinterpret_cast<const float4*>(s + 4);

    float ss = v0.x * v0.x + v0.y * v0.y + v0.z * v0.z + v0.w * v0.w
             + v1.x * v1.x + v1.y * v1.y + v1.z * v1.z + v1.w * v1.w;

    alignas(16) __hip_bfloat16 h[8];
    h[0] = __float2bfloat16(v0.x); h[1] = __float2bfloat16(v0.y);
    h[2] = __float2bfloat16(v0.z); h[3] = __float2bfloat16(v0.w);
    h[4] = __float2bfloat16(v1.x); h[5] = __float2bfloat16(v1.y);
    h[6] = __float2bfloat16(v1.z); h[7] = __float2bfloat16(v1.w);

    const int r = row & 127;
    const size_t di = ((size_t)((row >> 7) * 16 + (lane >> 2)) * 128 + r) * 32
                    + (((lane & 3) ^ ((r >> 1) & 3)) << 3);
    *reinterpret_cast<uint4*>((isP ? Pp : Fp) + di) =
        *reinterpret_cast<const uint4*>(h);

    #pragma unroll
    for (int off = 32; off > 0; off >>= 1) ss += __shfl_down(ss, off, 64);
    if (lane == 0) (isP ? p2 : f2)[row] = ss;
}

// ---- fused: 128x128 bf16 GEMM + e=exp(sim) + same-XCD last-block normalize.
// K-loop/epilogue identical to the proven r8 kernel. Handoff WITHOUT
// __threadfence: stores retire at L2 (vmcnt(0)); all 16 blocks of a panel run
// on the SAME XCD (swizzle) -> one L2 is the coherence point; e/partial lines
// are never loaded before the finisher, so no stale L1 copies can exist.
__global__ __launch_bounds__(256, 4)
void gemm_fused(const ushort* __restrict__ Fp,
                const ushort* __restrict__ Pp,
                const float* __restrict__ f2,
                const float* __restrict__ p2,
                float* __restrict__ out,
                float* __restrict__ partial,
                int* __restrict__ cnt) {
    __shared__ ushort lds[16384];   // 32 KB: dbuf A/B in K-loop; e-tile in epi
    __shared__ float rsums[128][2];
    __shared__ int finisher;

    ushort* eb = (ushort*)out;      // e lives in bytes [8192r, 8192r+4096)

    const int tid = threadIdx.x;
    const int wid = tid >> 6;
    const int ln  = tid & 63;
    const int lr  = ln & 15;
    const int lg  = ln >> 4;
    const int wr  = wid >> 1;       // wave row 0..1
    const int wc  = wid & 1;        // wave col 0..1

    // XCD-chunked bijective swizzle (nwg=4096): all 16 blocks of a row-panel
    // land on the SAME XCD; its 4MB L2 holds the panel's 1MB e + partials.
    const int orig = blockIdx.x;
    const int wg   = (orig & 7) * 512 + (orig >> 3);
    const int rb   = wg >> 4;
    const int cb   = wg & 15;
    const int row0 = rb * 128;
    const int col0 = cb * 128;

    const ushort* Asrc = Fp + (size_t)rb * 16 * 4096;
    const ushort* Bsrc = Pp + (size_t)cb * 16 * 4096;

    auto stage = [&](int c, int buf) {
        #pragma unroll
        for (int h = 0; h < 2; ++h) {
            gload16(Asrc + (size_t)c * 4096 + h * 2048 + tid * 8,
                    (char*)lds + buf * 16384 + h * 4096 + wid * 1024);
            gload16(Bsrc + (size_t)c * 4096 + h * 2048 + tid * 8,
                    (char*)lds + buf * 16384 + 8192 + h * 4096 + wid * 1024);
        }
    };

    f4v acc[4][4];
    #pragma unroll
    for (int m = 0; m < 4; ++m)
        #pragma unroll
        for (int n = 0; n < 4; ++n)
            acc[m][n] = (f4v){0.f, 0.f, 0.f, 0.f};

    stage(0, 0);
    stage(1, 1);

    const int swz = (lg ^ ((lr >> 1) & 3)) << 4;

    for (int c = 0; c < 16; ++c) {
        if (c < 15) asm volatile("s_waitcnt vmcnt(4)" ::: "memory");
        else        asm volatile("s_waitcnt vmcnt(0)" ::: "memory");
        __builtin_amdgcn_s_barrier();
        __builtin_amdgcn_sched_barrier(0);

        const char* Ab = (const char*)lds + (c & 1) * 16384;
        const char* Bb = Ab + 8192;
        s8v af[4], bf[4];
        #pragma unroll
        for (int m = 0; m < 4; ++m)
            af[m] = *reinterpret_cast<const s8v*>(Ab + (wr * 64 + m * 16 + lr) * 64 + swz);
        #pragma unroll
        for (int n = 0; n < 4; ++n)
            bf[n] = *reinterpret_cast<const s8v*>(Bb + (wc * 64 + n * 16 + lr) * 64 + swz);
        #pragma unroll
        for (int m = 0; m < 4; ++m)
            #pragma unroll
            for (int n = 0; n < 4; ++n)
                acc[m][n] = __builtin_amdgcn_mfma_f32_16x16x32_bf16(
                    af[m], bf[n], acc[m][n], 0, 0, 0);

        asm volatile("s_waitcnt lgkmcnt(0)" ::: "memory");
        __builtin_amdgcn_s_barrier();
        __builtin_amdgcn_sched_barrier(0);
        if (c < 14) stage(c + 2, c & 1);
    }

    // ---- epilogue: e = exp(1/(1+sqrt(f2+p2-2fp))), FAST math ---------------
    float pf2v[4][4];
    #pragma unroll
    for (int m = 0; m < 4; ++m)
        #pragma unroll
        for (int r = 0; r < 4; ++r)
            pf2v[m][r] = f2[row0 + wr * 64 + m * 16 + 4 * lg + r];

    float pp2v[4];
    #pragma unroll
    for (int n = 0; n < 4; ++n)
        pp2v[n] = p2[col0 + wc * 64 + n * 16 + lr];

    float rs[4][4];
    #pragma unroll
    for (int m = 0; m < 4; ++m)
        #pragma unroll
        for (int r = 0; r < 4; ++r)
            rs[m][r] = 0.f;

    #pragma unroll
    for (int m = 0; m < 4; ++m)
        #pragma unroll
        for (int n = 0; n < 4; ++n)
            #pragma unroll
            for (int r = 0; r < 4; ++r) {
                float sq = pf2v[m][r] + pp2v[n] - 2.0f * acc[m][n][r];
                sq = fmaxf(sq, 1e-20f);
                float d   = sq * __frsqrt_rn(sq);          // = sqrt(sq)
                float sim = __fdividef(1.0f, 1.0f + d);
                float e   = __expf(sim);
                rs[m][r] += e;
                const int trow = wr * 64 + m * 16 + 4 * lg + r;
                const int tcol = wc * 64 + ((n ^ lg) * 16) + lr;
                lds[trow * 128 + tcol] =
                    __builtin_bit_cast(ushort, __float2bfloat16(e));
            }
    __syncthreads();

    #pragma unroll
    for (int it = 0; it < 8; ++it) {
        const int trow = it * 16 + (tid >> 4);
        const int gi   = tid & 15;                    // 16B group 0..15
        const int gs   = (gi & 12) | ((gi & 3) ^ ((trow >> 2) & 3));
        uint4 v = *reinterpret_cast<const uint4*>(lds + trow * 128 + gs * 8);
        *reinterpret_cast<uint4*>(eb + (size_t)(row0 + trow) * 4096 + col0 + gi * 8) = v;
    }

    #pragma unroll
    for (int m = 0; m < 4; ++m)
        #pragma unroll
        for (int r = 0; r < 4; ++r) {
            float v = rs[m][r];
            #pragma unroll
            for (int msk = 1; msk < 16; msk <<= 1) v += __shfl_xor(v, msk, 64);
            rs[m][r] = v;
        }

    if (lr == 0) {
        #pragma unroll
        for (int m = 0; m < 4; ++m)
            #pragma unroll
            for (int r = 0; r < 4; ++r)
                rsums[wr * 64 + m * 16 + 4 * lg + r][wc] = rs[m][r];
    }
    __syncthreads();

    if (tid < 128)
        partial[(size_t)(row0 + tid) * 16 + cb] = rsums[tid][0] + rsums[tid][1];

    // ---- fence-free same-XCD handoff --------------------------------------
    // vmcnt(0): this thread's e/partial stores are at L2 (the XCD coherence
    // point). Barrier: whole block done. One device-scope atomic per block.
    asm volatile("s_waitcnt vmcnt(0)" ::: "memory");
    __syncthreads();
    if (tid == 0)
        finisher = (atomicAdd(&cnt[rb], 1) == 15);
    __syncthreads();
    if (!finisher) return;
    asm volatile("" ::: "memory");   // pin loads after the atomic observation

    // normalize the whole panel (reads hit own-XCD L2). Per row: read ALL
    // 2048 bf16 e first, then write fp32 — same-wave ordering, as proven.
    for (int it = 0; it < 32; ++it) {
        const int row = row0 + it * 4 + wid;

        float p = partial[(size_t)row * 16 + lr];
        #pragma unroll
        for (int msk = 1; msk < 16; msk <<= 1) p += __shfl_xor(p, msk, 64);
        const float inv = 1.0f / p;

        s8v v[4];
        #pragma unroll
        for (int jt = 0; jt < 4; ++jt)
            v[jt] = *reinterpret_cast<const s8v*>(eb + (size_t)row * 4096 + jt * 512 + ln * 8);

        #pragma unroll
        for (int jt = 0; jt < 4; ++jt) {
            float4 w0, w1;
            w0.x = __uint_as_float((unsigned)(ushort)v[jt][0] << 16) * inv;
            w0.y = __uint_as_float((unsigned)(ushort)v[jt][1] << 16) * inv;
            w0.z = __uint_as_float((unsigned)(ushort)v[jt][2] << 16) * inv;
            w0.w = __uint_as_float((unsigned)(ushort)v[jt][3] << 16) * inv;
            w1.x = __uint_as_float((unsigned)(ushort)v[jt][4] << 16) * inv;
            w1.y = __uint_as_float((unsigned)(ushort)v[jt][5] << 16) * inv;
            w1.z = __uint_as_float((unsigned)(ushort)v[jt][6] << 16) * inv;
            w1.w = __uint_as_float((unsigned)(ushort)v[jt][7] << 16) * inv;
            float* o = out + (size_t)row * 2048 + jt * 512 + ln * 8;
            *reinterpret_cast<float4*>(o)     = w0;
            *reinterpret_cast<float4*>(o + 4) = w1;
        }
    }
}

extern "C" void kernel_launch(void* const* d_in, const int* in_sizes, int n_in,
                              void* d_out, int out_size, void* d_ws, size_t ws_size,
                              hipStream_t stream) {
    const float* features   = (const float*)d_in[0];
    const float* prototypes = (const float*)d_in[1];
    float* out = (float*)d_out;

    const int n = in_sizes[0] / D_DIM;   // 32768
    const int k = in_sizes[1] / D_DIM;   // 2048

    char* ws = (char*)d_ws;
    ushort* Fp = (ushort*)ws;                                  // 32 MB packed F
    ushort* Pp = (ushort*)(ws + (size_t)n * D_DIM * 2);        // 2 MB packed P
    float*  f2 = (float*)(ws + (size_t)(n + k) * D_DIM * 2);   // n floats
    float*  p2 = f2 + n;                                       // k floats
    float*  partial = p2 + k;                                  // n*16 floats (2 MB)
    int*    cnt = (int*)(partial + (size_t)n * 16);            // n/128 ints

    hipMemsetAsync(cnt, 0, (n / 128) * sizeof(int), stream);

    prep_kernel<<<dim3((n + k + 3) / 4), dim3(256), 0, stream>>>(
        features, prototypes, Fp, Pp, f2, p2, n, n + k);

    const int nwg = (n / 128) * (k / 128);   // 4096
    gemm_fused<<<dim3(nwg), dim3(256), 0, stream>>>(Fp, Pp, f2, p2, out,
                                                    partial, cnt);
}

// Round 13
// 192.696 us; speedup vs baseline: 1.3364x; 1.3364x over previous
//
#include <hip/hip_runtime.h>
#include <hip/hip_bf16.h>

#define D_DIM 512
#define K_CL  2048

#define AS1 __attribute__((address_space(1)))
#define AS3 __attribute__((address_space(3)))

typedef short s8v __attribute__((ext_vector_type(8)));
typedef float f4v __attribute__((ext_vector_type(4)));

__device__ __forceinline__ void gload16(const void* g, void* l) {
    // async global->LDS, 16B/lane; LDS dest = wave-uniform base + lane*16
    __builtin_amdgcn_global_load_lds((const AS1 void*)g, (AS3 void*)l, 16, 0, 0);
}

// ---- merged prep: fp32 -> bf16 packed-tile images + row sum-of-squares -----
// Rows [0,n) = features -> Fp/f2; rows [n,n+k) = prototypes -> Pp/p2.
// Packed image: per 128-row panel pb, per 32-k chunk c: 4096-ushort block at
// (pb*16+c)*4096; row r at r*32, k-octet j at slot (j ^ ((r>>1)&3))*8.
__global__ void prep_kernel(const float* __restrict__ F,
                            const float* __restrict__ P,
                            ushort* __restrict__ Fp,
                            ushort* __restrict__ Pp,
                            float* __restrict__ f2,
                            float* __restrict__ p2,
                            int n, int ntot) {
    int grow = (int)((blockIdx.x * blockDim.x + threadIdx.x) >> 6);
    int lane = threadIdx.x & 63;
    if (grow >= ntot) return;

    const bool isP = grow >= n;
    const int  row = isP ? grow - n : grow;
    const float* s = (isP ? P : F) + (size_t)row * D_DIM + lane * 8;

    float4 v0 = *reinterpret_cast<const float4*>(s);
    float4 v1 = *reinterpret_cast<const float4*>(s + 4);

    float ss = v0.x * v0.x + v0.y * v0.y + v0.z * v0.z + v0.w * v0.w
             + v1.x * v1.x + v1.y * v1.y + v1.z * v1.z + v1.w * v1.w;

    alignas(16) __hip_bfloat16 h[8];
    h[0] = __float2bfloat16(v0.x); h[1] = __float2bfloat16(v0.y);
    h[2] = __float2bfloat16(v0.z); h[3] = __float2bfloat16(v0.w);
    h[4] = __float2bfloat16(v1.x); h[5] = __float2bfloat16(v1.y);
    h[6] = __float2bfloat16(v1.z); h[7] = __float2bfloat16(v1.w);

    const int r = row & 127;
    const size_t di = ((size_t)((row >> 7) * 16 + (lane >> 2)) * 128 + r) * 32
                    + (((lane & 3) ^ ((r >> 1) & 3)) << 3);
    *reinterpret_cast<uint4*>((isP ? Pp : Fp) + di) =
        *reinterpret_cast<const uint4*>(h);

    #pragma unroll
    for (int off = 32; off > 0; off >>= 1) ss += __shfl_down(ss, off, 64);
    if (lane == 0) (isP ? p2 : f2)[row] = ss;
}

// ---- pass 1: 128x128-tile bf16 GEMM + e=exp(sim), bf16 e-tile + partial sums
// 4 waves (2x2 of 64x64), BK=32, double-buffered LDS, counted vmcnt schedule.
// Proven r8 configuration (194.7 us total).
__global__ __launch_bounds__(256, 4)
void gemm_pass1(const ushort* __restrict__ Fp,
                const ushort* __restrict__ Pp,
                const float* __restrict__ f2,
                const float* __restrict__ p2,
                ushort* __restrict__ eb,
                float* __restrict__ partial) {
    __shared__ ushort lds[16384];   // 32 KB: dbuf A/B in K-loop; e-tile in epi
    __shared__ float rsums[128][2];

    const int tid = threadIdx.x;
    const int wid = tid >> 6;
    const int ln  = tid & 63;
    const int lr  = ln & 15;
    const int lg  = ln >> 4;
    const int wr  = wid >> 1;       // wave row 0..1
    const int wc  = wid & 1;        // wave col 0..1

    // XCD-chunked bijective swizzle (nwg=4096, 4096%8==0)
    const int orig = blockIdx.x;
    const int wg   = (orig & 7) * 512 + (orig >> 3);
    const int rb   = wg >> 4;
    const int cb   = wg & 15;
    const int row0 = rb * 128;
    const int col0 = cb * 128;

    const ushort* Asrc = Fp + (size_t)rb * 16 * 4096;
    const ushort* Bsrc = Pp + (size_t)cb * 16 * 4096;

    auto stage = [&](int c, int buf) {
        #pragma unroll
        for (int h = 0; h < 2; ++h) {
            gload16(Asrc + (size_t)c * 4096 + h * 2048 + tid * 8,
                    (char*)lds + buf * 16384 + h * 4096 + wid * 1024);
            gload16(Bsrc + (size_t)c * 4096 + h * 2048 + tid * 8,
                    (char*)lds + buf * 16384 + 8192 + h * 4096 + wid * 1024);
        }
    };

    f4v acc[4][4];
    #pragma unroll
    for (int m = 0; m < 4; ++m)
        #pragma unroll
        for (int n = 0; n < 4; ++n)
            acc[m][n] = (f4v){0.f, 0.f, 0.f, 0.f};

    // prologue: two tiles in flight (8 loads/wave outstanding)
    stage(0, 0);
    stage(1, 1);

    const int swz = (lg ^ ((lr >> 1) & 3)) << 4;   // swizzled 16B slot offset

    for (int c = 0; c < 16; ++c) {
        // retire stage(c) (4 oldest loads); stage(c+1) stays in flight
        if (c < 15) asm volatile("s_waitcnt vmcnt(4)" ::: "memory");
        else        asm volatile("s_waitcnt vmcnt(0)" ::: "memory");
        __builtin_amdgcn_s_barrier();
        __builtin_amdgcn_sched_barrier(0);

        const char* Ab = (const char*)lds + (c & 1) * 16384;
        const char* Bb = Ab + 8192;
        s8v af[4], bf[4];
        #pragma unroll
        for (int m = 0; m < 4; ++m)
            af[m] = *reinterpret_cast<const s8v*>(Ab + (wr * 64 + m * 16 + lr) * 64 + swz);
        #pragma unroll
        for (int n = 0; n < 4; ++n)
            bf[n] = *reinterpret_cast<const s8v*>(Bb + (wc * 64 + n * 16 + lr) * 64 + swz);
        #pragma unroll
        for (int m = 0; m < 4; ++m)
            #pragma unroll
            for (int n = 0; n < 4; ++n)
                acc[m][n] = __builtin_amdgcn_mfma_f32_16x16x32_bf16(
                    af[m], bf[n], acc[m][n], 0, 0, 0);

        // all LDS reads of buf c retired -> safe for stage(c+2) to overwrite
        asm volatile("s_waitcnt lgkmcnt(0)" ::: "memory");
        __builtin_amdgcn_s_barrier();
        __builtin_amdgcn_sched_barrier(0);
        if (c < 14) stage(c + 2, c & 1);
    }

    // ---- epilogue: e = exp(1/(1+sqrt(f2+p2-2fp))), FAST math ---------------
    float pf2v[4][4];
    #pragma unroll
    for (int m = 0; m < 4; ++m)
        #pragma unroll
        for (int r = 0; r < 4; ++r)
            pf2v[m][r] = f2[row0 + wr * 64 + m * 16 + 4 * lg + r];

    float pp2v[4];
    #pragma unroll
    for (int n = 0; n < 4; ++n)
        pp2v[n] = p2[col0 + wc * 64 + n * 16 + lr];

    float rs[4][4];
    #pragma unroll
    for (int m = 0; m < 4; ++m)
        #pragma unroll
        for (int r = 0; r < 4; ++r)
            rs[m][r] = 0.f;

    // e-tile into LDS (128x128 ushort), column-group XOR swizzle (n ^ lg)
    #pragma unroll
    for (int m = 0; m < 4; ++m)
        #pragma unroll
        for (int n = 0; n < 4; ++n)
            #pragma unroll
            for (int r = 0; r < 4; ++r) {
                float sq = pf2v[m][r] + pp2v[n] - 2.0f * acc[m][n][r];
                sq = fmaxf(sq, 1e-20f);
                float d   = sq * __frsqrt_rn(sq);          // = sqrt(sq)
                float sim = __fdividef(1.0f, 1.0f + d);
                float e   = __expf(sim);
                rs[m][r] += e;
                const int trow = wr * 64 + m * 16 + 4 * lg + r;
                const int tcol = wc * 64 + ((n ^ lg) * 16) + lr;
                lds[trow * 128 + tcol] =
                    __builtin_bit_cast(ushort, __float2bfloat16(e));
            }
    __syncthreads();

    // coalesced store: lane reads its 16B with the same group-XOR undone
    #pragma unroll
    for (int it = 0; it < 8; ++it) {
        const int trow = it * 16 + (tid >> 4);
        const int gi   = tid & 15;                    // 16B group 0..15
        const int gs   = (gi & 12) | ((gi & 3) ^ ((trow >> 2) & 3));
        uint4 v = *reinterpret_cast<const uint4*>(lds + trow * 128 + gs * 8);
        *reinterpret_cast<uint4*>(eb + (size_t)(row0 + trow) * 4096 + col0 + gi * 8) = v;
    }

    #pragma unroll
    for (int m = 0; m < 4; ++m)
        #pragma unroll
        for (int r = 0; r < 4; ++r) {
            float v = rs[m][r];
            #pragma unroll
            for (int msk = 1; msk < 16; msk <<= 1) v += __shfl_xor(v, msk, 64);
            rs[m][r] = v;
        }

    if (lr == 0) {
        #pragma unroll
        for (int m = 0; m < 4; ++m)
            #pragma unroll
            for (int r = 0; r < 4; ++r)
                rsums[wr * 64 + m * 16 + 4 * lg + r][wc] = rs[m][r];
    }
    __syncthreads();

    if (tid < 128)
        partial[(size_t)(row0 + tid) * 16 + cb] = rsums[tid][0] + rsums[tid][1];
}

// ---- pass 2: per-row normalize. e (bf16) lives in the row's own out slot:
// bytes [8192r, 8192r+4096). Read ALL of the row first, then write fp32.
__global__ __launch_bounds__(256)
void scale_kernel(const float* __restrict__ partial, float* __restrict__ out) {
    const ushort* eb = (const ushort*)out;
    const int wid = threadIdx.x >> 6;
    const int ln  = threadIdx.x & 63;
    const int row = blockIdx.x * 4 + wid;

    float p = partial[(size_t)row * 16 + (ln & 15)];
    #pragma unroll
    for (int msk = 1; msk < 16; msk <<= 1) p += __shfl_xor(p, msk, 64);
    const float inv = 1.0f / p;

    s8v v[4];
    #pragma unroll
    for (int it = 0; it < 4; ++it)
        v[it] = *reinterpret_cast<const s8v*>(eb + (size_t)row * 4096 + it * 512 + ln * 8);

    #pragma unroll
    for (int it = 0; it < 4; ++it) {
        float4 w0, w1;
        w0.x = __uint_as_float((unsigned)(ushort)v[it][0] << 16) * inv;
        w0.y = __uint_as_float((unsigned)(ushort)v[it][1] << 16) * inv;
        w0.z = __uint_as_float((unsigned)(ushort)v[it][2] << 16) * inv;
        w0.w = __uint_as_float((unsigned)(ushort)v[it][3] << 16) * inv;
        w1.x = __uint_as_float((unsigned)(ushort)v[it][4] << 16) * inv;
        w1.y = __uint_as_float((unsigned)(ushort)v[it][5] << 16) * inv;
        w1.z = __uint_as_float((unsigned)(ushort)v[it][6] << 16) * inv;
        w1.w = __uint_as_float((unsigned)(ushort)v[it][7] << 16) * inv;
        float* o = out + (size_t)row * 2048 + it * 512 + ln * 8;
        *reinterpret_cast<float4*>(o)     = w0;
        *reinterpret_cast<float4*>(o + 4) = w1;
    }
}

extern "C" void kernel_launch(void* const* d_in, const int* in_sizes, int n_in,
                              void* d_out, int out_size, void* d_ws, size_t ws_size,
                              hipStream_t stream) {
    const float* features   = (const float*)d_in[0];
    const float* prototypes = (const float*)d_in[1];
    float* out = (float*)d_out;

    const int n = in_sizes[0] / D_DIM;   // 32768
    const int k = in_sizes[1] / D_DIM;   // 2048

    char* ws = (char*)d_ws;
    ushort* Fp = (ushort*)ws;                                  // 32 MB packed F
    ushort* Pp = (ushort*)(ws + (size_t)n * D_DIM * 2);        // 2 MB packed P
    float*  f2 = (float*)(ws + (size_t)(n + k) * D_DIM * 2);   // n floats
    float*  p2 = f2 + n;                                       // k floats
    float*  partial = p2 + k;                                  // n*16 floats (2 MB)

    prep_kernel<<<dim3((n + k + 3) / 4), dim3(256), 0, stream>>>(
        features, prototypes, Fp, Pp, f2, p2, n, n + k);

    const int nwg = (n / 128) * (k / 128);   // 4096
    gemm_pass1<<<dim3(nwg), dim3(256), 0, stream>>>(Fp, Pp, f2, p2,
                                                    (ushort*)d_out, partial);

    scale_kernel<<<dim3(n / 4), dim3(256), 0, stream>>>(partial, out);
}